// Round 12
// baseline (66.755 us; speedup 1.0000x reference)
//
#include <hip/hip_runtime.h>
#include <hip/hip_bf16.h>

#define Bn 4
#define Nn 512
#define Tn 10
#define Fn 516      // N + 4
#define MH 128      // MSG_HID
#define MD 32       // MSG_DIM
#define UH 128      // UPD_HID
#define OD 4        // OUT_DIM

#define JSPLIT 64
#define JPB (Nn / JSPLIT)   // 8 j's per block
#define XTF (Tn * Fn)

typedef __attribute__((ext_vector_type(4))) short short4v;  // 4 bf16 = 2 VGPRs
typedef __attribute__((ext_vector_type(8))) short short8v;
typedef __attribute__((ext_vector_type(4))) float floatx4;

static __device__ inline unsigned pk2(float a, float b) {
  union { __hip_bfloat162 h; unsigned u; } cv;
  cv.h = __float22bfloat162_rn(make_float2(a, b));
  return cv.u;
}
static __device__ inline short4v pack4(float a, float b, float c, float d) {
  union { short4v s; unsigned u[2]; } cv;
  cv.u[0] = pk2(a, b);
  cv.u[1] = pk2(c, d);
  return cv.s;
}
// relu+pack two K16 D-tiles (even,odd khid halves) into one K=32 A-frag (k = 8q+e)
static __device__ inline short8v pack8r(floatx4 a, floatx4 b) {
  union { short8v s; unsigned u[4]; } cv;
  cv.u[0] = pk2(fmaxf(a[0], 0.f), fmaxf(a[1], 0.f));
  cv.u[1] = pk2(fmaxf(a[2], 0.f), fmaxf(a[3], 0.f));
  cv.u[2] = pk2(fmaxf(b[0], 0.f), fmaxf(b[1], 0.f));
  cv.u[3] = pk2(fmaxf(b[2], 0.f), fmaxf(b[3], 0.f));
  return cv.s;
}

// K=16 bf16 MFMA. A/B frag: lane(ln,q) elem e -> k = 4q+e. D: row m = 4q+r, col n = ln.
#if __has_builtin(__builtin_amdgcn_mfma_f32_16x16x16bf16_1k)
static __device__ inline floatx4 MFMA16(short4v a, short4v b, floatx4 c) {
  return __builtin_amdgcn_mfma_f32_16x16x16bf16_1k(a, b, c, 0, 0, 0);
}
#else
// Fallback: K=16 data in elems 0-3 of the K=32 op pairs k-wise; zero tail is exact.
static __device__ inline floatx4 MFMA16(short4v a, short4v b, floatx4 c) {
  short8v a8 = {a[0], a[1], a[2], a[3], 0, 0, 0, 0};
  short8v b8 = {b[0], b[1], b[2], b[3], 0, 0, 0, 0};
  return __builtin_amdgcn_mfma_f32_16x16x32_bf16(a8, b8, c, 0, 0, 0);
}
#endif
// K=32: A/B frag k = 8q+e (HW-verified in R2). Same C/D layout (row 4q+r, col ln).
static __device__ inline floatx4 MFMA32(short8v a, short8v b, floatx4 c) {
  return __builtin_amdgcn_mfma_f32_16x16x32_bf16(a, b, c, 0, 0, 0);
}

// ---------------- Kernel A: Abase[b*N+j][128] = mb1 + sum_{t,c<4} x[b,j,t,c]*mW1[5t+c][:]
__global__ __launch_bounds__(128) void kA(const float* __restrict__ x,
                                          const float* __restrict__ mW1,
                                          const float* __restrict__ mb1,
                                          float* __restrict__ Abase) {
  int bj = blockIdx.x;
  int k  = threadIdx.x;
  const float* xr = x + (size_t)bj * Tn * Fn;
  float acc = mb1[k];
#pragma unroll
  for (int t = 0; t < Tn; ++t)
#pragma unroll
    for (int c = 0; c < 4; ++c)
      acc = fmaf(xr[t * Fn + c], mW1[(t * 5 + c) * MH + k], acc);
  Abase[(size_t)bj * MH + k] = acc;
}

// ---------------- Kernel E: Ex[(b*N+j)*N + i][16] = bf16(x[b,j,t,4+i]), t>=10 -> 0.
__global__ __launch_bounds__(256) void kE(const float* __restrict__ x,
                                          __hip_bfloat16* __restrict__ Ex) {
  const int bj  = blockIdx.x;
  const int tid = threadIdx.x;
  const int w   = tid >> 6;
  const int l   = tid & 63;
  __shared__ uint4 rly[4][2][64];            // 8 KB, wave-private slices

  const float* xr = x + (size_t)bj * XTF + 4;
#pragma unroll
  for (int h = 0; h < 2; ++h) {
    int i = h * 256 + tid;
    float v[Tn];
#pragma unroll
    for (int t = 0; t < Tn; ++t) v[t] = xr[(size_t)t * Fn + i];

    union { unsigned u[8]; uint4 q[2]; } o;
#pragma unroll
    for (int p = 0; p < 5; ++p) o.u[p] = pk2(v[2 * p], v[2 * p + 1]);
    o.u[5] = 0u; o.u[6] = 0u; o.u[7] = 0u;

    rly[w][0][l] = o.q[0];                   // t 0..7
    rly[w][1][l] = o.q[1];                   // t 8..15
    // wave-private: in-order LDS within the wave.
    uint4* ob = (uint4*)(Ex + ((size_t)bj * Nn + h * 256 + w * 64) * 16);
    ob[l]      = rly[w][l & 1][l >> 1];
    ob[64 + l] = rly[w][l & 1][32 + (l >> 1)];
  }
}

// ---------------- Kernel B: chained MFMA pair-MLP, K=32 GEMM2 via khid permutation.
// sigma(mt, m) = (mt>>1)*32 + (m>>2)*8 + (m&3) + (mt&1)*4  (bijective over 128)
// GEMM1 tile mt computes P[sigma(mt,m)][i'] (16x16x16, K=t); lane q's D-regs from
// tile pair (2g,2g+1) are khid g*32+8q+{0..7} = the native K=32 A-frag ->
// GEMM2 uses mfma_f32_16x16x32_bf16. Zero shuffles.
__global__ __launch_bounds__(256, 4) void kB(const __hip_bfloat16* __restrict__ Ex,
                                             const float* __restrict__ Abase,
                                             const float* __restrict__ mW1,
                                             const float* __restrict__ mW2,
                                             float* __restrict__ msum) {
  const int bx    = blockIdx.x;              // B * 4 * JSPLIT = 1024
  const int jsp   = bx & (JSPLIT - 1);
  const int itile = (bx >> 6) & 3;
  const int b     = bx >> 8;
  const int tid   = threadIdx.x;
  const int w     = tid >> 6;                // wave -> 32-wide i slice
  const int l     = tid & 63;
  const int ln    = l & 15;
  const int q     = l >> 4;
  const int ibase = itile * 128 + w * 32;

  __shared__ float ciL[JPB][MH];             // 4 KB: Abase rows for this block's 8 j's
  {
    const float4* src = (const float4*)(Abase + (size_t)(b * Nn + jsp * JPB) * MH);
    ((float4*)&ciL[0][0])[tid] = src[tid];   // 256 float4 = 8x128 floats
  }

  // ---- all 16 E-frag loads issued up front (8 j x 2 nt), 8B each, coalesced
  short4v B1a[JPB][2];
#pragma unroll
  for (int jj = 0; jj < JPB; ++jj) {
    const __hip_bfloat16* ep =
        Ex + ((size_t)(b * Nn + jsp * JPB + jj) * Nn + ibase) * 16 + q * 4;
#pragma unroll
    for (int nt = 0; nt < 2; ++nt)
      B1a[jj][nt] = *(const short4v*)(ep + (nt * 16 + ln) * 16);
  }

  // ---- A1 frags with permuted khid rows: khid = sigma(mt, ln), k = t (zero t>=10)
  short4v A1[8];
#pragma unroll
  for (int mt = 0; mt < 8; ++mt) {
    int khid = (mt >> 1) * 32 + (ln >> 2) * 8 + (ln & 3) + (mt & 1) * 4;
    float v[4];
#pragma unroll
    for (int e = 0; e < 4; ++e) {
      int t = q * 4 + e;
      v[e] = (t < Tn) ? mW1[(t * 5 + 4) * MH + khid] : 0.f;
    }
    A1[mt] = pack4(v[0], v[1], v[2], v[3]);
  }
  // ---- B2x frags for K=32 GEMM2: elem e <-> khid row g*32 + 8q + e
  short8v B2x[4][2];
#pragma unroll
  for (int g = 0; g < 4; ++g)
#pragma unroll
    for (int ct = 0; ct < 2; ++ct) {
      union { short8v s; unsigned u[4]; } cv;
#pragma unroll
      for (int p = 0; p < 4; ++p) {
        float va = mW2[(g * 32 + q * 8 + 2 * p) * MD + ct * 16 + ln];
        float vb = mW2[(g * 32 + q * 8 + 2 * p + 1) * MD + ct * 16 + ln];
        cv.u[p] = pk2(va, vb);
      }
      B2x[g][ct] = cv.s;
    }

  floatx4 acc[2][2];
#pragma unroll
  for (int a = 0; a < 2; ++a)
#pragma unroll
    for (int c = 0; c < 2; ++c) acc[a][c] = (floatx4)0.f;

  __syncthreads();   // ciL ready

#pragma unroll
  for (int jj = 0; jj < JPB; ++jj) {
#pragma unroll
    for (int g = 0; g < 4; ++g) {
      // C-inputs: sigma(2g,4q+r) = g*32+8q+r ; sigma(2g+1,.) = +4 -> contiguous f4
      floatx4 ciE = *(const floatx4*)&ciL[jj][g * 32 + q * 8];
      floatx4 ciO = *(const floatx4*)&ciL[jj][g * 32 + 4 + q * 8];
      floatx4 dE0 = MFMA16(A1[2 * g],     B1a[jj][0], ciE);
      floatx4 dE1 = MFMA16(A1[2 * g],     B1a[jj][1], ciE);
      floatx4 dO0 = MFMA16(A1[2 * g + 1], B1a[jj][0], ciO);
      floatx4 dO1 = MFMA16(A1[2 * g + 1], B1a[jj][1], ciO);
      short8v pa0 = pack8r(dE0, dO0);    // K=32 A-frag, khid g*32+8q+e
      short8v pa1 = pack8r(dE1, dO1);
      acc[0][0] = MFMA32(pa0, B2x[g][0], acc[0][0]);
      acc[0][1] = MFMA32(pa0, B2x[g][1], acc[0][1]);
      acc[1][0] = MFMA32(pa1, B2x[g][0], acc[1][0]);
      acc[1][1] = MFMA32(pa1, B2x[g][1], acc[1][1]);
    }
  }

  // ---- accumulate into msum: i = ibase + nt*16 + 4q + r, c = ct*16 + ln
#pragma unroll
  for (int nt = 0; nt < 2; ++nt)
#pragma unroll
    for (int ct = 0; ct < 2; ++ct)
#pragma unroll
      for (int r = 0; r < 4; ++r) {
        int i = ibase + nt * 16 + q * 4 + r;
        int c = ct * 16 + ln;
        atomicAdd(&msum[(size_t)(b * Nn + i) * MD + c], acc[nt][ct][r]);
      }
}

// ---------------- Kernel C: per (b,i) final MLP 36 -> 128 -> 4
__global__ __launch_bounds__(128) void kC(const float* __restrict__ x,
                                          const float* __restrict__ msum,
                                          const float* __restrict__ mb2,
                                          const float* __restrict__ iW1,
                                          const float* __restrict__ ib1,
                                          const float* __restrict__ iW2,
                                          const float* __restrict__ ib2,
                                          float* __restrict__ out) {
  int bi = blockIdx.x;
  int k  = threadIdx.x;
  __shared__ float red[UH][OD];

  const float* ms = msum + (size_t)bi * MD;
  const float* nf = x + ((size_t)bi * Tn + (Tn - 1)) * Fn;

  float a = ib1[k];
#pragma unroll
  for (int c = 0; c < MD; ++c)
    a = fmaf(ms[c] + (float)Nn * mb2[c], iW1[c * UH + k], a);
#pragma unroll
  for (int c = 0; c < 4; ++c)
    a = fmaf(nf[c], iW1[(MD + c) * UH + k], a);
  a = fmaxf(a, 0.f);
#pragma unroll
  for (int c = 0; c < OD; ++c) red[k][c] = a * iW2[k * OD + c];
  __syncthreads();

  if (k < OD) {
    float s = ib2[k];
    for (int kk = 0; kk < UH; ++kk) s += red[kk][k];
    out[(size_t)bi * OD + k] = s;
  }
}

extern "C" void kernel_launch(void* const* d_in, const int* in_sizes, int n_in,
                              void* d_out, int out_size, void* d_ws, size_t ws_size,
                              hipStream_t stream) {
  const float* x   = (const float*)d_in[0];
  const float* mW1 = (const float*)d_in[1];
  const float* mb1 = (const float*)d_in[2];
  const float* mW2 = (const float*)d_in[3];
  const float* mb2 = (const float*)d_in[4];
  const float* iW1 = (const float*)d_in[5];
  const float* ib1 = (const float*)d_in[6];
  const float* iW2 = (const float*)d_in[7];
  const float* ib2 = (const float*)d_in[8];
  float* out = (float*)d_out;

  float* Abase = (float*)d_ws;                                   // 1 MB
  float* msum  = Abase + (size_t)Bn * Nn * MH;                   // 256 KB
  __hip_bfloat16* Ex = (__hip_bfloat16*)(msum + (size_t)Bn * Nn * MD);  // 33.5 MB

  hipMemsetAsync(msum, 0, (size_t)Bn * Nn * MD * sizeof(float), stream);

  kA<<<Bn * Nn, 128, 0, stream>>>(x, mW1, mb1, Abase);
  kE<<<Bn * Nn, 256, 0, stream>>>(x, Ex);
  kB<<<Bn * 4 * JSPLIT, 256, 0, stream>>>(Ex, Abase, mW1, mW2, msum);
  kC<<<Bn * Nn, 128, 0, stream>>>(x, msum, mb2, iW1, ib1, iW2, ib2, out);
}